// Round 7
// baseline (591.132 us; speedup 1.0000x reference)
//
#include <hip/hip_runtime.h>
#include <hip/hip_bf16.h>

#define NND 100000
#define NE  1600000
#define CC  32
#define LL  4
#define NC  (NND * CC)      // 3,200,000
#define NLC (NND * LL * CC) // 12,800,000
#define NBLK ((NND + 255) / 256)   // 391
#define NTILE (NND / 16)    // 6250
#define ETGRID 4096          // persistent edgetri blocks

typedef unsigned short u16;
typedef unsigned int u32;
typedef __attribute__((ext_vector_type(8))) short short8;
typedef __attribute__((ext_vector_type(4))) float float4v;

__device__ __forceinline__ u16 f2bfraw(float x) {
    __hip_bfloat16 h = __float2bfloat16(x);
    return *(u16*)&h;
}
__device__ __forceinline__ float blo(u32 v) { return __uint_as_float(v << 16); }
__device__ __forceinline__ float bhi(u32 v) { return __uint_as_float(v & 0xffff0000u); }
// fast silu: v_rcp_f32 instead of exact division (rel err ~1e-6, fine vs thr)
__device__ __forceinline__ float silu_f(float x) {
    return x * __builtin_amdgcn_rcpf(1.f + __expf(-x));
}

// ---- hist: count edges per source node -------------------------------------
__global__ __launch_bounds__(256) void hist_kernel(
    const int* __restrict__ ei0, int* __restrict__ hist)
{
    int e = blockIdx.x * 256 + threadIdx.x;
    if (e < NE) atomicAdd(&hist[ei0[e]], 1);
}

// ---- scan stage A: per-block sums ------------------------------------------
__global__ __launch_bounds__(256) void reduce_kernel(
    const int* __restrict__ hist, int* __restrict__ partial)
{
    __shared__ int sm[256];
    int b = blockIdx.x, t = threadIdx.x;
    int i = b * 256 + t;
    sm[t] = (i < NND) ? hist[i] : 0;
    __syncthreads();
    for (int off = 128; off > 0; off >>= 1) {
        if (t < off) sm[t] += sm[t + off];
        __syncthreads();
    }
    if (t == 0) partial[b] = sm[0];
}

// ---- scan stage B: single-block scan of NBLK partials ----------------------
__global__ __launch_bounds__(512) void scanp_kernel(
    const int* __restrict__ partial, int* __restrict__ poffset,
    int* __restrict__ row_start)
{
    __shared__ int tmp[512];
    int t = threadIdx.x;
    int v = (t < NBLK) ? partial[t] : 0;
    tmp[t] = v;
    __syncthreads();
    for (int off = 1; off < 512; off <<= 1) {
        int x = (t >= off) ? tmp[t - off] : 0;
        __syncthreads();
        tmp[t] += x;
        __syncthreads();
    }
    if (t < NBLK) poffset[t] = tmp[t] - v;
    if (t == 0) row_start[NND] = NE;
}

// ---- scan stage C: per-block exclusive scan + block offset -----------------
__global__ __launch_bounds__(256) void scanb_kernel(
    const int* __restrict__ hist, const int* __restrict__ poffset,
    int* __restrict__ row_start, int* __restrict__ cursor)
{
    __shared__ int tmp[256];
    int b = blockIdx.x, t = threadIdx.x;
    int i = b * 256 + t;
    int v = (i < NND) ? hist[i] : 0;
    tmp[t] = v;
    __syncthreads();
    for (int off = 1; off < 256; off <<= 1) {
        int x = (t >= off) ? tmp[t - off] : 0;
        __syncthreads();
        tmp[t] += x;
        __syncthreads();
    }
    int ex = tmp[t] - v + poffset[b];
    if (i < NND) { row_start[i] = ex; cursor[i] = ex; }
}

// ---- scatter: edges into CSR order, (dest,weight) packed in ONE uint2 ------
// also folds the f fp32->bf16 conversion (NC == 2*NE: 2 elems/thread).
__global__ __launch_bounds__(256) void scatter_kernel(
    const int* __restrict__ ei0, const int* __restrict__ ei1,
    const float* __restrict__ ew, int* __restrict__ cursor,
    uint2* __restrict__ esort,
    const float* __restrict__ f, u32* __restrict__ fb32)
{
    int e = blockIdx.x * 256 + threadIdx.x;
    if (e < NE) {
        float2 fv = *(const float2*)(f + (size_t)e * 2);
        fb32[e] = ((u32)f2bfraw(fv.y) << 16) | (u32)f2bfraw(fv.x);
        int s = ei0[e];
        int pos = atomicAdd(&cursor[s], 1);
        uint2 v;
        v.x = (u32)ei1[e];
        v.y = __float_as_uint(ew[e]);
        esort[pos] = v;
    }
}

// ---- prep: weights -> MFMA B-fragment order (bf16) -------------------------
// B-frag layout for 16x16x32: lane holds B[k=(lane>>4)*8+j][n=lane&15]
// KfFrag and KFrag are CONTIGUOUS (node_mfma stages both as one 24 KB blob).
__global__ __launch_bounds__(256) void prepw_kernel(
    const float* __restrict__ K, const float* __restrict__ Kf,
    u16* __restrict__ KfFrag,   // [l][kt][nt] x [64 lanes][8]
    u16* __restrict__ KFrag)    // [l][nt]     x [64 lanes][8]
{
    int t = threadIdx.x;
    for (int idx = t; idx < 16 * 64; idx += 256) {
        int fr = idx >> 6, ln = idx & 63;
        int l = fr >> 2, kt = (fr >> 1) & 1, nt = fr & 1;
        for (int j = 0; j < 8; ++j)
            KfFrag[idx * 8 + j] = f2bfraw(
                Kf[l * 2048 + (kt * 32 + (ln >> 4) * 8 + j) * 32 + nt * 16 + (ln & 15)]);
    }
    for (int idx = t; idx < 8 * 64; idx += 256) {
        int fr = idx >> 6, ln = idx & 63;
        int l = fr >> 1, nt = fr & 1;
        for (int j = 0; j < 8; ++j)
            KFrag[idx * 8 + j] = f2bfraw(
                K[l * 1024 + ((ln >> 4) * 8 + j) * 32 + nt * 16 + (ln & 15)]);
    }
}

// ---- node via MFMA: dz[n][c][l] = (silu([Z_nl,f_n]@Kf_l)@K_l)[c] -----------
// r4-proven config: weight frags staged global->LDS once per BLOCK, grid 1563
// (1 tile/wave). FIRST variant skips the Z operand on fixpoint iteration 0
// (Z==0): no zero-read, no memset. (r5's reg-weights@782 regressed: +17 us.)
template<bool FIRST>
__global__ __launch_bounds__(256) void node_mfma_kernel(
    const u16* __restrict__ Zb,     // [N][L][C] bf16 raw (unused if FIRST)
    const u16* __restrict__ fb,     // [N][C] bf16 raw
    const u16* __restrict__ WFrag,  // KfFrag ++ KFrag, 12288 u16 = 24 KB
    uint2* __restrict__ dzv)        // [N][C] ushort4 (ws)
{
    __shared__ __attribute__((aligned(16))) ushort sW[12288];
    __shared__ __attribute__((aligned(16))) ushort trs[4 * 16 * 72];
    const int tid = threadIdx.x;
    {   // cooperative 24 KB stage: 1536 uint4 / 256 threads = 6 each
        const uint4* g = (const uint4*)WFrag;
        uint4* s = (uint4*)sW;
        for (int i = tid; i < 1536; i += 256) s[i] = g[i];
    }
    __syncthreads();
    const int wv = tid >> 6, lane = tid & 63;
    const int m = lane & 15, quad = lane >> 4;
    const short8* kfp = (const short8*)sW;           // 16 Kf frags
    const short8* kp  = (const short8*)(sW + 8192);  // 8 K frags
    ushort* tr = trs + wv * (16 * 72);   // row stride 72 u16: 16B-aligned rows

    for (int tile = blockIdx.x * 4 + wv; tile < NTILE; tile += gridDim.x * 4) {
        int na = tile * 16 + m;          // A-operand node
        short8 fa = *(const short8*)(fb + na * 32 + quad * 8);
        uint2 pk[8];
#pragma unroll
        for (int i = 0; i < 8; ++i) { pk[i].x = 0u; pk[i].y = 0u; }
#pragma unroll
        for (int l = 0; l < LL; ++l) {
            float4v c0 = {0.f, 0.f, 0.f, 0.f};
            float4v c1 = {0.f, 0.f, 0.f, 0.f};
            if (!FIRST) {
                short8 za = *(const short8*)(Zb + na * 128 + l * 32 + quad * 8);
                c0 = __builtin_amdgcn_mfma_f32_16x16x32_bf16(za, kfp[(l * 4 + 0) * 64 + lane], c0, 0, 0, 0);
                c1 = __builtin_amdgcn_mfma_f32_16x16x32_bf16(za, kfp[(l * 4 + 1) * 64 + lane], c1, 0, 0, 0);
            }
            c0 = __builtin_amdgcn_mfma_f32_16x16x32_bf16(fa, kfp[(l * 4 + 2) * 64 + lane], c0, 0, 0, 0);
            c1 = __builtin_amdgcn_mfma_f32_16x16x32_bf16(fa, kfp[(l * 4 + 3) * 64 + lane], c1, 0, 0, 0);
            // D layout: lane holds D[node'=quad*4+r][ch=nt*16+m]; silu -> LDS
#pragma unroll
            for (int r = 0; r < 4; ++r) {
                tr[(quad * 4 + r) * 72 + m]      = f2bfraw(silu_f(c0[r]));
                tr[(quad * 4 + r) * 72 + 16 + m] = f2bfraw(silu_f(c1[r]));
            }
            asm volatile("s_waitcnt lgkmcnt(0)" ::: "memory");  // same-wave RAW
            // A2[m=lane&15][k=quad*8+j] from LDS tile [node][ch]
            short8 a2 = *(const short8*)(tr + m * 72 + quad * 8);
            float4v d0 = {0.f, 0.f, 0.f, 0.f};
            float4v d1 = {0.f, 0.f, 0.f, 0.f};
            d0 = __builtin_amdgcn_mfma_f32_16x16x32_bf16(a2, kp[(l * 2 + 0) * 64 + lane], d0, 0, 0, 0);
            d1 = __builtin_amdgcn_mfma_f32_16x16x32_bf16(a2, kp[(l * 2 + 1) * 64 + lane], d1, 0, 0, 0);
#pragma unroll
            for (int r = 0; r < 4; ++r) {
                u32 b0 = f2bfraw(d0[r]);
                u32 b1 = f2bfraw(d1[r]);
                if (l == 0)      { pk[r].x |= b0;       pk[4 + r].x |= b1; }
                else if (l == 1) { pk[r].x |= b0 << 16; pk[4 + r].x |= b1 << 16; }
                else if (l == 2) { pk[r].y |= b0;       pk[4 + r].y |= b1; }
                else             { pk[r].y |= b0 << 16; pk[4 + r].y |= b1 << 16; }
            }
        }
#pragma unroll
        for (int r = 0; r < 4; ++r) {
            int node = tile * 16 + quad * 4 + r;
            dzv[node * 32 + m]      = pk[r];
            dzv[node * 32 + 16 + m] = pk[4 + r];
        }
    }
}

// ---- fused edge + tri: persistent blocks, ONE node per wave ----------------
// v8 = r4 structure + node-level software pipelining of the per-node serial
// front-end: row_start/self-row prefetched one node ahead at loop top; the
// next node's first 64-edge chunk prefetched right after the current node's
// first gathers are issued. Gather concurrency UNCHANGED (3 in flight) --
// preserves the measured L2 miss equilibrium (FETCH ~200 MB), only the
// coalesced header loads are overlapped with compute.
// EPI=0: write Z bf16 full-lines via LDS repack. EPI=1: write fp32 out.
template<int EPI>
__global__ __launch_bounds__(256) void edgetri_kernel(
    const uint4* __restrict__ dzq,          // [N][16] uint4 rows (ws)
    const int* __restrict__ row_start,
    const uint2* __restrict__ esort,        // [NE] (dest, weight) (ws)
    const float* __restrict__ K,            // [L][C][C]
    const float* __restrict__ X,            // [N][C]
    u16* __restrict__ Z,                    // [N][L][C] bf16 (d_out scratch)
    float* __restrict__ out)                // [NC + NLC] fp32 (d_out)
{
    __shared__ float sKt[LL][CC][CC + 1];   // [l][k][c] = K[l][c][k]
    __shared__ float sAg[4][LL][CC];
    __shared__ __attribute__((aligned(16))) ushort sZr[4][128]; // Z repack
    const int tid = threadIdx.x;
    for (int j = tid; j < LL * CC * CC; j += 256) {
        int l = j >> 10, k = (j >> 5) & 31, cx = j & 31;
        sKt[l][k][cx] = K[l * 1024 + cx * CC + k];
    }
    const int wv = tid >> 6, lane = tid & 63;
    const int g = lane >> 4, u = lane & 15;
    const int h = lane >> 5, c = lane & 31;
    __syncthreads();

    const int STR = ETGRID * 4;
    const int n0 = blockIdx.x * 4 + wv;     // always < NND (16384 waves)
    // prologue prefetch for the first node
    int e0 = row_start[n0];
    int e1 = row_start[n0 + 1];
    uint4 sq = dzq[(size_t)n0 * 16 + u];
    uint2 ev; ev.x = 0u; ev.y = 0u;
    {
        int cnt0 = min(64, e1 - e0);
        if (lane < cnt0) ev = esort[e0 + lane];
    }

    for (int n = n0; n < NND; n += STR) {
        const int nn = n + STR;
        const int e0c = e0, e1c = e1;
        const uint2 evc = ev;
        const uint4 sqc = sq;
        if (nn < NND) {             // prefetch next node's row ptrs + self row
            e0 = row_start[nn];
            e1 = row_start[nn + 1];
            sq = dzq[(size_t)nn * 16 + u];
        }
        float s00 = blo(sqc.x), s01 = bhi(sqc.x), s02 = blo(sqc.y), s03 = bhi(sqc.y);
        float s10 = blo(sqc.z), s11 = bhi(sqc.z), s12 = blo(sqc.w), s13 = bhi(sqc.w);
        float a00 = 0.f, a01 = 0.f, a02 = 0.f, a03 = 0.f;
        float a10 = 0.f, a11 = 0.f, a12 = 0.f, a13 = 0.f;

        for (int base = e0c; base < e1c; base += 64) {
            const int cnt = min(64, e1c - base);    // wave-uniform
            const int iters = (cnt + 3) >> 2;       // wave-uniform
            uint2 evx;
            if (base == e0c) {
                evx = evc;                           // prefetched chunk
            } else {                                 // rare: deg > 64
                evx.x = 0u; evx.y = 0u;
                if (lane < cnt) evx = esort[base + lane];
            }
            int   idxL = (int)evx.x;
            float wL   = __uint_as_float(evx.y);

            // pipeline prologue: slots 0 and 1 (uniform branches)
            int j0 = g;
            int   d0 = __shfl(idxL, j0);
            float w0 = __shfl(wL, j0);
            uint4 z0 = dzq[(size_t)d0 * 16 + u];
            float w1 = 0.f; uint4 z1 = z0;
            if (iters > 1) {
                int jn = j0 + 4;
                int dn = __shfl(idxL, jn);
                w1 = __shfl(wL, jn);
                z1 = dzq[(size_t)dn * 16 + u];
            }
            // prefetch NEXT node's first edge chunk now: its row ptrs were
            // issued at loop top; consumption is a whole node away.
            if (base == e0c) {
                ev.x = 0u; ev.y = 0u;
                if (nn < NND) {
                    int cn = min(64, e1 - e0);
                    if (lane < cn) ev = esort[e0 + lane];
                }
            }
            int jj = j0;
            for (int k = 0; k < iters; ++k) {
                float w2 = 0.f; uint4 z2 = z0;
                if (k + 2 < iters) {                // wave-uniform
                    int jn = jj + 8;
                    int dn = __shfl(idxL, jn);
                    w2 = __shfl(wL, jn);
                    z2 = dzq[(size_t)dn * 16 + u];
                }
                a00 += silu_f(w0 * (s00 - blo(z0.x)));
                a01 += silu_f(w0 * (s01 - bhi(z0.x)));
                a02 += silu_f(w0 * (s02 - blo(z0.y)));
                a03 += silu_f(w0 * (s03 - bhi(z0.y)));
                a10 += silu_f(w0 * (s10 - blo(z0.z)));
                a11 += silu_f(w0 * (s11 - bhi(z0.z)));
                a12 += silu_f(w0 * (s12 - blo(z0.w)));
                a13 += silu_f(w0 * (s13 - bhi(z0.w)));
                jj += 4;
                w0 = w1; z0 = z1;
                w1 = w2; z1 = z2;
            }
        }

        a00 += __shfl_xor(a00, 16); a00 += __shfl_xor(a00, 32);
        a01 += __shfl_xor(a01, 16); a01 += __shfl_xor(a01, 32);
        a02 += __shfl_xor(a02, 16); a02 += __shfl_xor(a02, 32);
        a03 += __shfl_xor(a03, 16); a03 += __shfl_xor(a03, 32);
        a10 += __shfl_xor(a10, 16); a10 += __shfl_xor(a10, 32);
        a11 += __shfl_xor(a11, 16); a11 += __shfl_xor(a11, 32);
        a12 += __shfl_xor(a12, 16); a12 += __shfl_xor(a12, 32);
        a13 += __shfl_xor(a13, 16); a13 += __shfl_xor(a13, 32);
        if (g == 0) {
            sAg[wv][0][2 * u]     = a00; sAg[wv][1][2 * u]     = a01;
            sAg[wv][2][2 * u]     = a02; sAg[wv][3][2 * u]     = a03;
            sAg[wv][0][2 * u + 1] = a10; sAg[wv][1][2 * u + 1] = a11;
            sAg[wv][2][2 * u + 1] = a12; sAg[wv][3][2 * u + 1] = a13;
        }
        int lA = h, lB = h + 2;
        float yA = 0.f, yB = 0.f;
#pragma unroll
        for (int k = 0; k < CC; ++k) {
            yA += sAg[wv][lA][k] * sKt[lA][k][c];
            yB += sAg[wv][lB][k] * sKt[lB][k][c];
        }
        yA = -yA; yB = -yB;
        float yAo = __shfl_xor(yA, 32);
        float yBo = __shfl_xor(yB, 32);
        if (h == 0) {
            float y0 = yA, y1 = yAo, y2 = yB, y3 = yBo;
            y3 += X[n * CC + c];
            const float c0 = 0.70710678118654752f;  // sqrt(1/2)
            const float c1 = 0.81649658092772603f;  // sqrt(2/3)
            const float c2 = 0.86602540378443865f;  // sqrt(3/4)
            const float c3 = 0.89442719099991588f;  // sqrt(4/5)
            float t0 = c0 * y0;
            float t1 = c1 * (c0 * t0 + y1);
            float t2 = c2 * (c1 * t1 + y2);
            float t3 = c3 * (c2 * t2 + y3);
            float w3 = c3 * t3;
            float w2 = c2 * (c2 * w3 + t2);
            float w1 = c1 * (c1 * w2 + t1);
            float w0 = c0 * (c0 * w1 + t0);
            if (EPI == 0) {
                // pack bf16 row into LDS; stored as full lines below
                sZr[wv][0 * CC + c] = f2bfraw(w0);
                sZr[wv][1 * CC + c] = f2bfraw(w1);
                sZr[wv][2 * CC + c] = f2bfraw(w2);
                sZr[wv][3 * CC + c] = f2bfraw(w3);
            } else {
                int rem = n * CC + c;
                out[rem] = w3;                       // Z[3] block
                out[NC + 0 * NC + rem] = w0;         // Z flat (L,N,C)
                out[NC + 1 * NC + rem] = w1;
                out[NC + 2 * NC + rem] = w2;
                out[NC + 3 * NC + rem] = w3;
            }
        }
        if (EPI == 0) {
            asm volatile("s_waitcnt lgkmcnt(0)" ::: "memory");  // same-wave RAW
            if (lane < 16) {
                uint4 zv = *(const uint4*)(&sZr[wv][lane * 8]);
                ((uint4*)(Z + (size_t)n * 128))[lane] = zv;     // 2 full lines
            }
        }
    }
}

extern "C" void kernel_launch(void* const* d_in, const int* in_sizes, int n_in,
                              void* d_out, int out_size, void* d_ws, size_t ws_size,
                              hipStream_t stream)
{
    const float* X  = (const float*)d_in[0];
    const float* f  = (const float*)d_in[1];
    const int* ei   = (const int*)d_in[2];
    const float* ew = (const float*)d_in[3];
    const float* K  = (const float*)d_in[4];
    const float* Kf = (const float*)d_in[5];
    float* out = (float*)d_out;

    // ws layout (~46 MB of the >=51.2 MB workspace):
    //   dz 25.6 MB | fb 6.4 MB | frags 24 KB | ints ~1.2 MB | esort 12.8 MB
    char* ws = (char*)d_ws;
    uint2* dzv = (uint2*)ws;                                 // [N][C] ushort4
    const uint4* dzq = (const uint4*)ws;
    u16* fb        = (u16*)(ws + (size_t)NC * 8);            // NC bf16
    u16* KfFrag    = fb + NC;                                // 8192 u16
    u16* KFrag     = KfFrag + 16 * 64 * 8;                   // 4096 u16 (contiguous!)
    int* hist      = (int*)(KFrag + 8 * 64 * 8);             // NND
    int* cursor    = hist + NND;                             // NND
    int* row_start = cursor + NND;                           // NND+1
    int* partial   = row_start + (NND + 1);                  // NBLK
    int* poffset   = partial + NBLK;                         // NBLK
    size_t eoff = ((size_t)((char*)(poffset + NBLK) - ws) + 15) & ~(size_t)15;
    uint2* esort   = (uint2*)(ws + eoff);                    // NE uint2 = 12.8 MB

    // Z bf16 [N][L][C] = 25.6 MB lives in d_out scratch; fully written by
    // edgetri<0>, fully read by node_mfma<false>, dead before edgetri<1>
    // overwrites d_out with the final fp32 output.
    u16* Z = (u16*)d_out;

    const int* ei0 = ei;
    const int* ei1 = ei + NE;

    hipMemsetAsync(hist, 0, (size_t)NND * sizeof(int), stream);

    // one-time prep: CSR sort + bf16 conversions + weight frag swizzle
    hist_kernel<<<NE / 256, 256, 0, stream>>>(ei0, hist);
    reduce_kernel<<<NBLK, 256, 0, stream>>>(hist, partial);
    scanp_kernel<<<1, 512, 0, stream>>>(partial, poffset, row_start);
    scanb_kernel<<<NBLK, 256, 0, stream>>>(hist, poffset, row_start, cursor);
    scatter_kernel<<<NE / 256, 256, 0, stream>>>(ei0, ei1, ew, cursor, esort,
                                                 f, (u32*)fb);
    prepw_kernel<<<1, 256, 0, stream>>>(K, Kf, KfFrag, KFrag);

    // fixpoint iteration 0: Z == 0 (no memset, no Z reads)
    node_mfma_kernel<true><<<1563, 256, 0, stream>>>((const u16*)Z, fb, KfFrag, dzv);
    edgetri_kernel<0><<<ETGRID, 256, 0, stream>>>(dzq, row_start, esort, K, X, Z, out);
    // fixpoint iteration 1: read Z, write final fp32 out directly
    node_mfma_kernel<false><<<1563, 256, 0, stream>>>((const u16*)Z, fb, KfFrag, dzv);
    edgetri_kernel<1><<<ETGRID, 256, 0, stream>>>(dzq, row_start, esort, K, X, Z, out);
}

// Round 8
// 576.803 us; speedup vs baseline: 1.0248x; 1.0248x over previous
//
#include <hip/hip_runtime.h>
#include <hip/hip_bf16.h>

#define NND 100000
#define NE  1600000
#define CC  32
#define LL  4
#define NC  (NND * CC)      // 3,200,000
#define NLC (NND * LL * CC) // 12,800,000
#define NBLK ((NND + 255) / 256)   // 391
#define NTILE (NND / 16)    // 6250
#define ETGRID 4096          // persistent edgetri blocks

typedef unsigned short u16;
typedef unsigned int u32;
typedef __attribute__((ext_vector_type(8))) short short8;
typedef __attribute__((ext_vector_type(4))) float float4v;

__device__ __forceinline__ u16 f2bfraw(float x) {
    __hip_bfloat16 h = __float2bfloat16(x);
    return *(u16*)&h;
}
__device__ __forceinline__ float blo(u32 v) { return __uint_as_float(v << 16); }
__device__ __forceinline__ float bhi(u32 v) { return __uint_as_float(v & 0xffff0000u); }
// fast silu: v_rcp_f32 instead of exact division (rel err ~1e-6, fine vs thr)
__device__ __forceinline__ float silu_f(float x) {
    return x * __builtin_amdgcn_rcpf(1.f + __expf(-x));
}
// packed edge: dest (17b) << 15 | w * 32767 (15b fixed-point).
// w quant err <= 1.5e-5 abs -- ~4x below the existing bf16-dz error.
__device__ __forceinline__ void edec(u32 uu, int& d, float& w) {
    d = (int)(uu >> 15);
    w = (float)(uu & 0x7fffu) * (1.f / 32767.f);
}

// ---- hist: count edges per source node -------------------------------------
__global__ __launch_bounds__(256) void hist_kernel(
    const int* __restrict__ ei0, int* __restrict__ hist)
{
    int e = blockIdx.x * 256 + threadIdx.x;
    if (e < NE) atomicAdd(&hist[ei0[e]], 1);
}

// ---- scan stage A: per-block sums ------------------------------------------
__global__ __launch_bounds__(256) void reduce_kernel(
    const int* __restrict__ hist, int* __restrict__ partial)
{
    __shared__ int sm[256];
    int b = blockIdx.x, t = threadIdx.x;
    int i = b * 256 + t;
    sm[t] = (i < NND) ? hist[i] : 0;
    __syncthreads();
    for (int off = 128; off > 0; off >>= 1) {
        if (t < off) sm[t] += sm[t + off];
        __syncthreads();
    }
    if (t == 0) partial[b] = sm[0];
}

// ---- scan stage B: single-block scan of NBLK partials ----------------------
__global__ __launch_bounds__(512) void scanp_kernel(
    const int* __restrict__ partial, int* __restrict__ poffset,
    int* __restrict__ row_start)
{
    __shared__ int tmp[512];
    int t = threadIdx.x;
    int v = (t < NBLK) ? partial[t] : 0;
    tmp[t] = v;
    __syncthreads();
    for (int off = 1; off < 512; off <<= 1) {
        int x = (t >= off) ? tmp[t - off] : 0;
        __syncthreads();
        tmp[t] += x;
        __syncthreads();
    }
    if (t < NBLK) poffset[t] = tmp[t] - v;
    if (t == 0) row_start[NND] = NE;
}

// ---- scan stage C: per-block exclusive scan + block offset -----------------
__global__ __launch_bounds__(256) void scanb_kernel(
    const int* __restrict__ hist, const int* __restrict__ poffset,
    int* __restrict__ row_start, int* __restrict__ cursor)
{
    __shared__ int tmp[256];
    int b = blockIdx.x, t = threadIdx.x;
    int i = b * 256 + t;
    int v = (i < NND) ? hist[i] : 0;
    tmp[t] = v;
    __syncthreads();
    for (int off = 1; off < 256; off <<= 1) {
        int x = (t >= off) ? tmp[t - off] : 0;
        __syncthreads();
        tmp[t] += x;
        __syncthreads();
    }
    int ex = tmp[t] - v + poffset[b];
    if (i < NND) { row_start[i] = ex; cursor[i] = ex; }
}

// ---- scatter: edges into CSR order, packed 4-B payload ---------------------
// (dest<<15 | w15) -- halves the random write-allocate footprint vs uint2.
// also folds the f fp32->bf16 conversion (NC == 2*NE: 2 elems/thread).
__global__ __launch_bounds__(256) void scatter_kernel(
    const int* __restrict__ ei0, const int* __restrict__ ei1,
    const float* __restrict__ ew, int* __restrict__ cursor,
    u32* __restrict__ esort,
    const float* __restrict__ f, u32* __restrict__ fb32)
{
    int e = blockIdx.x * 256 + threadIdx.x;
    if (e < NE) {
        float2 fv = *(const float2*)(f + (size_t)e * 2);
        fb32[e] = ((u32)f2bfraw(fv.y) << 16) | (u32)f2bfraw(fv.x);
        int s = ei0[e];
        int pos = atomicAdd(&cursor[s], 1);
        u32 wq = (u32)__float2uint_rn(ew[e] * 32767.f);
        esort[pos] = ((u32)ei1[e] << 15) | wq;
    }
}

// ---- prep: weights -> MFMA B-fragment order (bf16) -------------------------
// B-frag layout for 16x16x32: lane holds B[k=(lane>>4)*8+j][n=lane&15]
// KfFrag and KFrag are CONTIGUOUS (node_mfma stages both as one 24 KB blob).
__global__ __launch_bounds__(256) void prepw_kernel(
    const float* __restrict__ K, const float* __restrict__ Kf,
    u16* __restrict__ KfFrag,   // [l][kt][nt] x [64 lanes][8]
    u16* __restrict__ KFrag)    // [l][nt]     x [64 lanes][8]
{
    int t = threadIdx.x;
    for (int idx = t; idx < 16 * 64; idx += 256) {
        int fr = idx >> 6, ln = idx & 63;
        int l = fr >> 2, kt = (fr >> 1) & 1, nt = fr & 1;
        for (int j = 0; j < 8; ++j)
            KfFrag[idx * 8 + j] = f2bfraw(
                Kf[l * 2048 + (kt * 32 + (ln >> 4) * 8 + j) * 32 + nt * 16 + (ln & 15)]);
    }
    for (int idx = t; idx < 8 * 64; idx += 256) {
        int fr = idx >> 6, ln = idx & 63;
        int l = fr >> 1, nt = fr & 1;
        for (int j = 0; j < 8; ++j)
            KFrag[idx * 8 + j] = f2bfraw(
                K[l * 1024 + ((ln >> 4) * 8 + j) * 32 + nt * 16 + (ln & 15)]);
    }
}

// ---- node via MFMA: dz[n][c][l] = (silu([Z_nl,f_n]@Kf_l)@K_l)[c] -----------
// r4-proven config: weight frags staged global->LDS once per BLOCK, grid 1563
// (1 tile/wave). FIRST variant skips the Z operand on fixpoint iteration 0
// (Z==0): no zero-read, no memset. (r5's reg-weights@782 regressed: +17 us.)
template<bool FIRST>
__global__ __launch_bounds__(256) void node_mfma_kernel(
    const u16* __restrict__ Zb,     // [N][L][C] bf16 raw (unused if FIRST)
    const u16* __restrict__ fb,     // [N][C] bf16 raw
    const u16* __restrict__ WFrag,  // KfFrag ++ KFrag, 12288 u16 = 24 KB
    uint2* __restrict__ dzv)        // [N][C] ushort4 (ws)
{
    __shared__ __attribute__((aligned(16))) ushort sW[12288];
    __shared__ __attribute__((aligned(16))) ushort trs[4 * 16 * 72];
    const int tid = threadIdx.x;
    {   // cooperative 24 KB stage: 1536 uint4 / 256 threads = 6 each
        const uint4* g = (const uint4*)WFrag;
        uint4* s = (uint4*)sW;
        for (int i = tid; i < 1536; i += 256) s[i] = g[i];
    }
    __syncthreads();
    const int wv = tid >> 6, lane = tid & 63;
    const int m = lane & 15, quad = lane >> 4;
    const short8* kfp = (const short8*)sW;           // 16 Kf frags
    const short8* kp  = (const short8*)(sW + 8192);  // 8 K frags
    ushort* tr = trs + wv * (16 * 72);   // row stride 72 u16: 16B-aligned rows

    for (int tile = blockIdx.x * 4 + wv; tile < NTILE; tile += gridDim.x * 4) {
        int na = tile * 16 + m;          // A-operand node
        short8 fa = *(const short8*)(fb + na * 32 + quad * 8);
        uint2 pk[8];
#pragma unroll
        for (int i = 0; i < 8; ++i) { pk[i].x = 0u; pk[i].y = 0u; }
#pragma unroll
        for (int l = 0; l < LL; ++l) {
            float4v c0 = {0.f, 0.f, 0.f, 0.f};
            float4v c1 = {0.f, 0.f, 0.f, 0.f};
            if (!FIRST) {
                short8 za = *(const short8*)(Zb + na * 128 + l * 32 + quad * 8);
                c0 = __builtin_amdgcn_mfma_f32_16x16x32_bf16(za, kfp[(l * 4 + 0) * 64 + lane], c0, 0, 0, 0);
                c1 = __builtin_amdgcn_mfma_f32_16x16x32_bf16(za, kfp[(l * 4 + 1) * 64 + lane], c1, 0, 0, 0);
            }
            c0 = __builtin_amdgcn_mfma_f32_16x16x32_bf16(fa, kfp[(l * 4 + 2) * 64 + lane], c0, 0, 0, 0);
            c1 = __builtin_amdgcn_mfma_f32_16x16x32_bf16(fa, kfp[(l * 4 + 3) * 64 + lane], c1, 0, 0, 0);
            // D layout: lane holds D[node'=quad*4+r][ch=nt*16+m]; silu -> LDS
#pragma unroll
            for (int r = 0; r < 4; ++r) {
                tr[(quad * 4 + r) * 72 + m]      = f2bfraw(silu_f(c0[r]));
                tr[(quad * 4 + r) * 72 + 16 + m] = f2bfraw(silu_f(c1[r]));
            }
            asm volatile("s_waitcnt lgkmcnt(0)" ::: "memory");  // same-wave RAW
            // A2[m=lane&15][k=quad*8+j] from LDS tile [node][ch]
            short8 a2 = *(const short8*)(tr + m * 72 + quad * 8);
            float4v d0 = {0.f, 0.f, 0.f, 0.f};
            float4v d1 = {0.f, 0.f, 0.f, 0.f};
            d0 = __builtin_amdgcn_mfma_f32_16x16x32_bf16(a2, kp[(l * 2 + 0) * 64 + lane], d0, 0, 0, 0);
            d1 = __builtin_amdgcn_mfma_f32_16x16x32_bf16(a2, kp[(l * 2 + 1) * 64 + lane], d1, 0, 0, 0);
#pragma unroll
            for (int r = 0; r < 4; ++r) {
                u32 b0 = f2bfraw(d0[r]);
                u32 b1 = f2bfraw(d1[r]);
                if (l == 0)      { pk[r].x |= b0;       pk[4 + r].x |= b1; }
                else if (l == 1) { pk[r].x |= b0 << 16; pk[4 + r].x |= b1 << 16; }
                else if (l == 2) { pk[r].y |= b0;       pk[4 + r].y |= b1; }
                else             { pk[r].y |= b0 << 16; pk[4 + r].y |= b1 << 16; }
            }
        }
#pragma unroll
        for (int r = 0; r < 4; ++r) {
            int node = tile * 16 + quad * 4 + r;
            dzv[node * 32 + m]      = pk[r];
            dzv[node * 32 + 16 + m] = pk[4 + r];
        }
    }
}

// ---- fused edge + tri: persistent blocks, ONE node per wave ----------------
// v9 = v8 (node-level front-end pipelining) + packed 4-B esort: one shfl per
// edge slot instead of two, half the esort read volume. Gather concurrency
// unchanged (3 in flight) -- preserves the measured L2 miss equilibrium.
// EPI=0: write Z bf16 full-lines via LDS repack. EPI=1: write fp32 out.
template<int EPI>
__global__ __launch_bounds__(256) void edgetri_kernel(
    const uint4* __restrict__ dzq,          // [N][16] uint4 rows (ws)
    const int* __restrict__ row_start,
    const u32* __restrict__ esort,          // [NE] packed (dest,w15) (ws)
    const float* __restrict__ K,            // [L][C][C]
    const float* __restrict__ X,            // [N][C]
    u16* __restrict__ Z,                    // [N][L][C] bf16 (d_out scratch)
    float* __restrict__ out)                // [NC + NLC] fp32 (d_out)
{
    __shared__ float sKt[LL][CC][CC + 1];   // [l][k][c] = K[l][c][k]
    __shared__ float sAg[4][LL][CC];
    __shared__ __attribute__((aligned(16))) ushort sZr[4][128]; // Z repack
    const int tid = threadIdx.x;
    for (int j = tid; j < LL * CC * CC; j += 256) {
        int l = j >> 10, k = (j >> 5) & 31, cx = j & 31;
        sKt[l][k][cx] = K[l * 1024 + cx * CC + k];
    }
    const int wv = tid >> 6, lane = tid & 63;
    const int g = lane >> 4, u = lane & 15;
    const int h = lane >> 5, c = lane & 31;
    __syncthreads();

    const int STR = ETGRID * 4;
    const int n0 = blockIdx.x * 4 + wv;     // always < NND (16384 waves)
    // prologue prefetch for the first node
    int e0 = row_start[n0];
    int e1 = row_start[n0 + 1];
    uint4 sq = dzq[(size_t)n0 * 16 + u];
    u32 ev = 0u;
    {
        int cnt0 = min(64, e1 - e0);
        if (lane < cnt0) ev = esort[e0 + lane];
    }

    for (int n = n0; n < NND; n += STR) {
        const int nn = n + STR;
        const int e0c = e0, e1c = e1;
        const u32 evc = ev;
        const uint4 sqc = sq;
        if (nn < NND) {             // prefetch next node's row ptrs + self row
            e0 = row_start[nn];
            e1 = row_start[nn + 1];
            sq = dzq[(size_t)nn * 16 + u];
        }
        float s00 = blo(sqc.x), s01 = bhi(sqc.x), s02 = blo(sqc.y), s03 = bhi(sqc.y);
        float s10 = blo(sqc.z), s11 = bhi(sqc.z), s12 = blo(sqc.w), s13 = bhi(sqc.w);
        float a00 = 0.f, a01 = 0.f, a02 = 0.f, a03 = 0.f;
        float a10 = 0.f, a11 = 0.f, a12 = 0.f, a13 = 0.f;

        for (int base = e0c; base < e1c; base += 64) {
            const int cnt = min(64, e1c - base);    // wave-uniform
            const int iters = (cnt + 3) >> 2;       // wave-uniform
            u32 evx;
            if (base == e0c) {
                evx = evc;                           // prefetched chunk
            } else {                                 // rare: deg > 64
                evx = 0u;
                if (lane < cnt) evx = esort[base + lane];
            }

            // pipeline prologue: slots 0 and 1 (uniform branches)
            int j0 = g;
            int d0; float w0;
            edec((u32)__shfl((int)evx, j0), d0, w0);
            uint4 z0 = dzq[(size_t)d0 * 16 + u];
            float w1 = 0.f; uint4 z1 = z0;
            if (iters > 1) {
                int dn;
                edec((u32)__shfl((int)evx, j0 + 4), dn, w1);
                z1 = dzq[(size_t)dn * 16 + u];
            }
            // prefetch NEXT node's first edge chunk now: its row ptrs were
            // issued at loop top; consumption is a whole node away.
            if (base == e0c) {
                ev = 0u;
                if (nn < NND) {
                    int cn = min(64, e1 - e0);
                    if (lane < cn) ev = esort[e0 + lane];
                }
            }
            int jj = j0;
            for (int k = 0; k < iters; ++k) {
                float w2 = 0.f; uint4 z2 = z0;
                if (k + 2 < iters) {                // wave-uniform
                    int dn;
                    edec((u32)__shfl((int)evx, jj + 8), dn, w2);
                    z2 = dzq[(size_t)dn * 16 + u];
                }
                a00 += silu_f(w0 * (s00 - blo(z0.x)));
                a01 += silu_f(w0 * (s01 - bhi(z0.x)));
                a02 += silu_f(w0 * (s02 - blo(z0.y)));
                a03 += silu_f(w0 * (s03 - bhi(z0.y)));
                a10 += silu_f(w0 * (s10 - blo(z0.z)));
                a11 += silu_f(w0 * (s11 - bhi(z0.z)));
                a12 += silu_f(w0 * (s12 - blo(z0.w)));
                a13 += silu_f(w0 * (s13 - bhi(z0.w)));
                jj += 4;
                w0 = w1; z0 = z1;
                w1 = w2; z1 = z2;
            }
        }

        a00 += __shfl_xor(a00, 16); a00 += __shfl_xor(a00, 32);
        a01 += __shfl_xor(a01, 16); a01 += __shfl_xor(a01, 32);
        a02 += __shfl_xor(a02, 16); a02 += __shfl_xor(a02, 32);
        a03 += __shfl_xor(a03, 16); a03 += __shfl_xor(a03, 32);
        a10 += __shfl_xor(a10, 16); a10 += __shfl_xor(a10, 32);
        a11 += __shfl_xor(a11, 16); a11 += __shfl_xor(a11, 32);
        a12 += __shfl_xor(a12, 16); a12 += __shfl_xor(a12, 32);
        a13 += __shfl_xor(a13, 16); a13 += __shfl_xor(a13, 32);
        if (g == 0) {
            sAg[wv][0][2 * u]     = a00; sAg[wv][1][2 * u]     = a01;
            sAg[wv][2][2 * u]     = a02; sAg[wv][3][2 * u]     = a03;
            sAg[wv][0][2 * u + 1] = a10; sAg[wv][1][2 * u + 1] = a11;
            sAg[wv][2][2 * u + 1] = a12; sAg[wv][3][2 * u + 1] = a13;
        }
        int lA = h, lB = h + 2;
        float yA = 0.f, yB = 0.f;
#pragma unroll
        for (int k = 0; k < CC; ++k) {
            yA += sAg[wv][lA][k] * sKt[lA][k][c];
            yB += sAg[wv][lB][k] * sKt[lB][k][c];
        }
        yA = -yA; yB = -yB;
        float yAo = __shfl_xor(yA, 32);
        float yBo = __shfl_xor(yB, 32);
        if (h == 0) {
            float y0 = yA, y1 = yAo, y2 = yB, y3 = yBo;
            y3 += X[n * CC + c];
            const float c0 = 0.70710678118654752f;  // sqrt(1/2)
            const float c1 = 0.81649658092772603f;  // sqrt(2/3)
            const float c2 = 0.86602540378443865f;  // sqrt(3/4)
            const float c3 = 0.89442719099991588f;  // sqrt(4/5)
            float t0 = c0 * y0;
            float t1 = c1 * (c0 * t0 + y1);
            float t2 = c2 * (c1 * t1 + y2);
            float t3 = c3 * (c2 * t2 + y3);
            float w3 = c3 * t3;
            float w2 = c2 * (c2 * w3 + t2);
            float w1 = c1 * (c1 * w2 + t1);
            float w0 = c0 * (c0 * w1 + t0);
            if (EPI == 0) {
                // pack bf16 row into LDS; stored as full lines below
                sZr[wv][0 * CC + c] = f2bfraw(w0);
                sZr[wv][1 * CC + c] = f2bfraw(w1);
                sZr[wv][2 * CC + c] = f2bfraw(w2);
                sZr[wv][3 * CC + c] = f2bfraw(w3);
            } else {
                int rem = n * CC + c;
                out[rem] = w3;                       // Z[3] block
                out[NC + 0 * NC + rem] = w0;         // Z flat (L,N,C)
                out[NC + 1 * NC + rem] = w1;
                out[NC + 2 * NC + rem] = w2;
                out[NC + 3 * NC + rem] = w3;
            }
        }
        if (EPI == 0) {
            asm volatile("s_waitcnt lgkmcnt(0)" ::: "memory");  // same-wave RAW
            if (lane < 16) {
                uint4 zv = *(const uint4*)(&sZr[wv][lane * 8]);
                ((uint4*)(Z + (size_t)n * 128))[lane] = zv;     // 2 full lines
            }
        }
    }
}

extern "C" void kernel_launch(void* const* d_in, const int* in_sizes, int n_in,
                              void* d_out, int out_size, void* d_ws, size_t ws_size,
                              hipStream_t stream)
{
    const float* X  = (const float*)d_in[0];
    const float* f  = (const float*)d_in[1];
    const int* ei   = (const int*)d_in[2];
    const float* ew = (const float*)d_in[3];
    const float* K  = (const float*)d_in[4];
    const float* Kf = (const float*)d_in[5];
    float* out = (float*)d_out;

    // ws layout (~40 MB of the >=51.2 MB workspace):
    //   dz 25.6 MB | fb 6.4 MB | frags 24 KB | ints ~1.2 MB | esort 6.4 MB
    char* ws = (char*)d_ws;
    uint2* dzv = (uint2*)ws;                                 // [N][C] ushort4
    const uint4* dzq = (const uint4*)ws;
    u16* fb        = (u16*)(ws + (size_t)NC * 8);            // NC bf16
    u16* KfFrag    = fb + NC;                                // 8192 u16
    u16* KFrag     = KfFrag + 16 * 64 * 8;                   // 4096 u16 (contiguous!)
    int* hist      = (int*)(KFrag + 8 * 64 * 8);             // NND
    int* cursor    = hist + NND;                             // NND
    int* row_start = cursor + NND;                           // NND+1
    int* partial   = row_start + (NND + 1);                  // NBLK
    int* poffset   = partial + NBLK;                         // NBLK
    size_t eoff = ((size_t)((char*)(poffset + NBLK) - ws) + 15) & ~(size_t)15;
    u32* esort     = (u32*)(ws + eoff);                      // NE u32 = 6.4 MB

    // Z bf16 [N][L][C] = 25.6 MB lives in d_out scratch; fully written by
    // edgetri<0>, fully read by node_mfma<false>, dead before edgetri<1>
    // overwrites d_out with the final fp32 output.
    u16* Z = (u16*)d_out;

    const int* ei0 = ei;
    const int* ei1 = ei + NE;

    hipMemsetAsync(hist, 0, (size_t)NND * sizeof(int), stream);

    // one-time prep: CSR sort + bf16 conversions + weight frag swizzle
    hist_kernel<<<NE / 256, 256, 0, stream>>>(ei0, hist);
    reduce_kernel<<<NBLK, 256, 0, stream>>>(hist, partial);
    scanp_kernel<<<1, 512, 0, stream>>>(partial, poffset, row_start);
    scanb_kernel<<<NBLK, 256, 0, stream>>>(hist, poffset, row_start, cursor);
    scatter_kernel<<<NE / 256, 256, 0, stream>>>(ei0, ei1, ew, cursor, esort,
                                                 f, (u32*)fb);
    prepw_kernel<<<1, 256, 0, stream>>>(K, Kf, KfFrag, KFrag);

    // fixpoint iteration 0: Z == 0 (no memset, no Z reads)
    node_mfma_kernel<true><<<1563, 256, 0, stream>>>((const u16*)Z, fb, KfFrag, dzv);
    edgetri_kernel<0><<<ETGRID, 256, 0, stream>>>(dzq, row_start, esort, K, X, Z, out);
    // fixpoint iteration 1: read Z, write final fp32 out directly
    node_mfma_kernel<false><<<1563, 256, 0, stream>>>((const u16*)Z, fb, KfFrag, dzv);
    edgetri_kernel<1><<<ETGRID, 256, 0, stream>>>(dzq, row_start, esort, K, X, Z, out);
}

// Round 9
// 503.833 us; speedup vs baseline: 1.1733x; 1.1448x over previous
//
#include <hip/hip_runtime.h>
#include <hip/hip_bf16.h>

#define NND 100000
#define NE  1600000
#define CC  32
#define LL  4
#define NC  (NND * CC)      // 3,200,000
#define NLC (NND * LL * CC) // 12,800,000
#define NBLK ((NND + 255) / 256)   // 391
#define NTILE (NND / 16)    // 6250
#define ETGRID 4096          // persistent edgetri blocks

typedef unsigned short u16;
typedef unsigned int u32;
typedef __attribute__((ext_vector_type(8))) short short8;
typedef __attribute__((ext_vector_type(4))) float float4v;

__device__ __forceinline__ u16 f2bfraw(float x) {
    __hip_bfloat16 h = __float2bfloat16(x);
    return *(u16*)&h;
}
__device__ __forceinline__ float blo(u32 v) { return __uint_as_float(v << 16); }
__device__ __forceinline__ float bhi(u32 v) { return __uint_as_float(v & 0xffff0000u); }
// fast silu: v_rcp_f32 instead of exact division (rel err ~1e-6, fine vs thr)
__device__ __forceinline__ float silu_f(float x) {
    return x * __builtin_amdgcn_rcpf(1.f + __expf(-x));
}
// packed edge: dest (17b) << 15 | w * 32767 (15b fixed-point).
// w quant err <= 1.5e-5 abs -- ~4x below the existing bf16-dz error.
__device__ __forceinline__ void edec(u32 uu, int& d, float& w) {
    d = (int)(uu >> 15);
    w = (float)(uu & 0x7fffu) * (1.f / 32767.f);
}

// ---- hist + rank: count edges per source node, record per-edge rank --------
// the atomicAdd return value IS the edge's rank within its source node --
// this makes the scatter pass atomic-free (halves total device atomics).
__global__ __launch_bounds__(256) void histrank_kernel(
    const int* __restrict__ ei0, int* __restrict__ hist,
    int* __restrict__ rank)
{
    int e = blockIdx.x * 256 + threadIdx.x;
    if (e < NE) rank[e] = atomicAdd(&hist[ei0[e]], 1);
}

// ---- scan stage A: per-block sums ------------------------------------------
__global__ __launch_bounds__(256) void reduce_kernel(
    const int* __restrict__ hist, int* __restrict__ partial)
{
    __shared__ int sm[256];
    int b = blockIdx.x, t = threadIdx.x;
    int i = b * 256 + t;
    sm[t] = (i < NND) ? hist[i] : 0;
    __syncthreads();
    for (int off = 128; off > 0; off >>= 1) {
        if (t < off) sm[t] += sm[t + off];
        __syncthreads();
    }
    if (t == 0) partial[b] = sm[0];
}

// ---- scan stage B: single-block scan of NBLK partials ----------------------
__global__ __launch_bounds__(512) void scanp_kernel(
    const int* __restrict__ partial, int* __restrict__ poffset,
    int* __restrict__ row_start)
{
    __shared__ int tmp[512];
    int t = threadIdx.x;
    int v = (t < NBLK) ? partial[t] : 0;
    tmp[t] = v;
    __syncthreads();
    for (int off = 1; off < 512; off <<= 1) {
        int x = (t >= off) ? tmp[t - off] : 0;
        __syncthreads();
        tmp[t] += x;
        __syncthreads();
    }
    if (t < NBLK) poffset[t] = tmp[t] - v;
    if (t == 0) row_start[NND] = NE;
}

// ---- scan stage C: per-block exclusive scan + block offset -----------------
__global__ __launch_bounds__(256) void scanb_kernel(
    const int* __restrict__ hist, const int* __restrict__ poffset,
    int* __restrict__ row_start)
{
    __shared__ int tmp[256];
    int b = blockIdx.x, t = threadIdx.x;
    int i = b * 256 + t;
    int v = (i < NND) ? hist[i] : 0;
    tmp[t] = v;
    __syncthreads();
    for (int off = 1; off < 256; off <<= 1) {
        int x = (t >= off) ? tmp[t - off] : 0;
        __syncthreads();
        tmp[t] += x;
        __syncthreads();
    }
    int ex = tmp[t] - v + poffset[b];
    if (i < NND) row_start[i] = ex;
}

// ---- scatter: edges into CSR order, packed 4-B payload, NO atomics ---------
// pos = row_start[s] + rank[e] (rank captured during histogram).
// also folds the f fp32->bf16 conversion (NC == 2*NE: 2 elems/thread).
__global__ __launch_bounds__(256) void scatter_kernel(
    const int* __restrict__ ei0, const int* __restrict__ ei1,
    const float* __restrict__ ew,
    const int* __restrict__ row_start, const int* __restrict__ rank,
    u32* __restrict__ esort,
    const float* __restrict__ f, u32* __restrict__ fb32)
{
    int e = blockIdx.x * 256 + threadIdx.x;
    if (e < NE) {
        float2 fv = *(const float2*)(f + (size_t)e * 2);
        fb32[e] = ((u32)f2bfraw(fv.y) << 16) | (u32)f2bfraw(fv.x);
        int s = ei0[e];
        int pos = row_start[s] + rank[e];
        u32 wq = (u32)__float2uint_rn(ew[e] * 32767.f);
        esort[pos] = ((u32)ei1[e] << 15) | wq;
    }
}

// ---- prep: weights -> MFMA B-fragment order (bf16) -------------------------
// B-frag layout for 16x16x32: lane holds B[k=(lane>>4)*8+j][n=lane&15]
// KfFrag and KFrag are CONTIGUOUS (node_mfma stages both as one 24 KB blob).
__global__ __launch_bounds__(256) void prepw_kernel(
    const float* __restrict__ K, const float* __restrict__ Kf,
    u16* __restrict__ KfFrag,   // [l][kt][nt] x [64 lanes][8]
    u16* __restrict__ KFrag)    // [l][nt]     x [64 lanes][8]
{
    int t = threadIdx.x;
    for (int idx = t; idx < 16 * 64; idx += 256) {
        int fr = idx >> 6, ln = idx & 63;
        int l = fr >> 2, kt = (fr >> 1) & 1, nt = fr & 1;
        for (int j = 0; j < 8; ++j)
            KfFrag[idx * 8 + j] = f2bfraw(
                Kf[l * 2048 + (kt * 32 + (ln >> 4) * 8 + j) * 32 + nt * 16 + (ln & 15)]);
    }
    for (int idx = t; idx < 8 * 64; idx += 256) {
        int fr = idx >> 6, ln = idx & 63;
        int l = fr >> 1, nt = fr & 1;
        for (int j = 0; j < 8; ++j)
            KFrag[idx * 8 + j] = f2bfraw(
                K[l * 1024 + ((ln >> 4) * 8 + j) * 32 + nt * 16 + (ln & 15)]);
    }
}

// ---- node via MFMA: dz[n][c][l] = (silu([Z_nl,f_n]@Kf_l)@K_l)[c] -----------
// r4-proven config: weight frags staged global->LDS once per BLOCK, grid 1563
// (1 tile/wave). FIRST variant skips the Z operand on fixpoint iteration 0
// (Z==0): no zero-read, no memset. (r5's reg-weights@782 regressed: +17 us.)
template<bool FIRST>
__global__ __launch_bounds__(256) void node_mfma_kernel(
    const u16* __restrict__ Zb,     // [N][L][C] bf16 raw (unused if FIRST)
    const u16* __restrict__ fb,     // [N][C] bf16 raw
    const u16* __restrict__ WFrag,  // KfFrag ++ KFrag, 12288 u16 = 24 KB
    uint2* __restrict__ dzv)        // [N][C] ushort4 (ws)
{
    __shared__ __attribute__((aligned(16))) ushort sW[12288];
    __shared__ __attribute__((aligned(16))) ushort trs[4 * 16 * 72];
    const int tid = threadIdx.x;
    {   // cooperative 24 KB stage: 1536 uint4 / 256 threads = 6 each
        const uint4* g = (const uint4*)WFrag;
        uint4* s = (uint4*)sW;
        for (int i = tid; i < 1536; i += 256) s[i] = g[i];
    }
    __syncthreads();
    const int wv = tid >> 6, lane = tid & 63;
    const int m = lane & 15, quad = lane >> 4;
    const short8* kfp = (const short8*)sW;           // 16 Kf frags
    const short8* kp  = (const short8*)(sW + 8192);  // 8 K frags
    ushort* tr = trs + wv * (16 * 72);   // row stride 72 u16: 16B-aligned rows

    for (int tile = blockIdx.x * 4 + wv; tile < NTILE; tile += gridDim.x * 4) {
        int na = tile * 16 + m;          // A-operand node
        short8 fa = *(const short8*)(fb + na * 32 + quad * 8);
        uint2 pk[8];
#pragma unroll
        for (int i = 0; i < 8; ++i) { pk[i].x = 0u; pk[i].y = 0u; }
#pragma unroll
        for (int l = 0; l < LL; ++l) {
            float4v c0 = {0.f, 0.f, 0.f, 0.f};
            float4v c1 = {0.f, 0.f, 0.f, 0.f};
            if (!FIRST) {
                short8 za = *(const short8*)(Zb + na * 128 + l * 32 + quad * 8);
                c0 = __builtin_amdgcn_mfma_f32_16x16x32_bf16(za, kfp[(l * 4 + 0) * 64 + lane], c0, 0, 0, 0);
                c1 = __builtin_amdgcn_mfma_f32_16x16x32_bf16(za, kfp[(l * 4 + 1) * 64 + lane], c1, 0, 0, 0);
            }
            c0 = __builtin_amdgcn_mfma_f32_16x16x32_bf16(fa, kfp[(l * 4 + 2) * 64 + lane], c0, 0, 0, 0);
            c1 = __builtin_amdgcn_mfma_f32_16x16x32_bf16(fa, kfp[(l * 4 + 3) * 64 + lane], c1, 0, 0, 0);
            // D layout: lane holds D[node'=quad*4+r][ch=nt*16+m]; silu -> LDS
#pragma unroll
            for (int r = 0; r < 4; ++r) {
                tr[(quad * 4 + r) * 72 + m]      = f2bfraw(silu_f(c0[r]));
                tr[(quad * 4 + r) * 72 + 16 + m] = f2bfraw(silu_f(c1[r]));
            }
            asm volatile("s_waitcnt lgkmcnt(0)" ::: "memory");  // same-wave RAW
            // A2[m=lane&15][k=quad*8+j] from LDS tile [node][ch]
            short8 a2 = *(const short8*)(tr + m * 72 + quad * 8);
            float4v d0 = {0.f, 0.f, 0.f, 0.f};
            float4v d1 = {0.f, 0.f, 0.f, 0.f};
            d0 = __builtin_amdgcn_mfma_f32_16x16x32_bf16(a2, kp[(l * 2 + 0) * 64 + lane], d0, 0, 0, 0);
            d1 = __builtin_amdgcn_mfma_f32_16x16x32_bf16(a2, kp[(l * 2 + 1) * 64 + lane], d1, 0, 0, 0);
#pragma unroll
            for (int r = 0; r < 4; ++r) {
                u32 b0 = f2bfraw(d0[r]);
                u32 b1 = f2bfraw(d1[r]);
                if (l == 0)      { pk[r].x |= b0;       pk[4 + r].x |= b1; }
                else if (l == 1) { pk[r].x |= b0 << 16; pk[4 + r].x |= b1 << 16; }
                else if (l == 2) { pk[r].y |= b0;       pk[4 + r].y |= b1; }
                else             { pk[r].y |= b0 << 16; pk[4 + r].y |= b1 << 16; }
            }
        }
#pragma unroll
        for (int r = 0; r < 4; ++r) {
            int node = tile * 16 + quad * 4 + r;
            dzv[node * 32 + m]      = pk[r];
            dzv[node * 32 + 16 + m] = pk[4 + r];
        }
    }
}

// ---- fused edge + tri: persistent blocks, ONE node per wave ----------------
// v9 structure (frozen): node-level front-end pipelining + packed 4-B esort +
// 3-deep gather pipeline (measured L2-equilibrium: FETCH ~198 MB).
// EPI=0: write Z bf16 full-lines via LDS repack. EPI=1: write fp32 out.
template<int EPI>
__global__ __launch_bounds__(256) void edgetri_kernel(
    const uint4* __restrict__ dzq,          // [N][16] uint4 rows (ws)
    const int* __restrict__ row_start,
    const u32* __restrict__ esort,          // [NE] packed (dest,w15) (ws)
    const float* __restrict__ K,            // [L][C][C]
    const float* __restrict__ X,            // [N][C]
    u16* __restrict__ Z,                    // [N][L][C] bf16 (d_out scratch)
    float* __restrict__ out)                // [NC + NLC] fp32 (d_out)
{
    __shared__ float sKt[LL][CC][CC + 1];   // [l][k][c] = K[l][c][k]
    __shared__ float sAg[4][LL][CC];
    __shared__ __attribute__((aligned(16))) ushort sZr[4][128]; // Z repack
    const int tid = threadIdx.x;
    for (int j = tid; j < LL * CC * CC; j += 256) {
        int l = j >> 10, k = (j >> 5) & 31, cx = j & 31;
        sKt[l][k][cx] = K[l * 1024 + cx * CC + k];
    }
    const int wv = tid >> 6, lane = tid & 63;
    const int g = lane >> 4, u = lane & 15;
    const int h = lane >> 5, c = lane & 31;
    __syncthreads();

    const int STR = ETGRID * 4;
    const int n0 = blockIdx.x * 4 + wv;     // always < NND (16384 waves)
    // prologue prefetch for the first node
    int e0 = row_start[n0];
    int e1 = row_start[n0 + 1];
    uint4 sq = dzq[(size_t)n0 * 16 + u];
    u32 ev = 0u;
    {
        int cnt0 = min(64, e1 - e0);
        if (lane < cnt0) ev = esort[e0 + lane];
    }

    for (int n = n0; n < NND; n += STR) {
        const int nn = n + STR;
        const int e0c = e0, e1c = e1;
        const u32 evc = ev;
        const uint4 sqc = sq;
        if (nn < NND) {             // prefetch next node's row ptrs + self row
            e0 = row_start[nn];
            e1 = row_start[nn + 1];
            sq = dzq[(size_t)nn * 16 + u];
        }
        float s00 = blo(sqc.x), s01 = bhi(sqc.x), s02 = blo(sqc.y), s03 = bhi(sqc.y);
        float s10 = blo(sqc.z), s11 = bhi(sqc.z), s12 = blo(sqc.w), s13 = bhi(sqc.w);
        float a00 = 0.f, a01 = 0.f, a02 = 0.f, a03 = 0.f;
        float a10 = 0.f, a11 = 0.f, a12 = 0.f, a13 = 0.f;

        for (int base = e0c; base < e1c; base += 64) {
            const int cnt = min(64, e1c - base);    // wave-uniform
            const int iters = (cnt + 3) >> 2;       // wave-uniform
            u32 evx;
            if (base == e0c) {
                evx = evc;                           // prefetched chunk
            } else {                                 // rare: deg > 64
                evx = 0u;
                if (lane < cnt) evx = esort[base + lane];
            }

            // pipeline prologue: slots 0 and 1 (uniform branches)
            int j0 = g;
            int d0; float w0;
            edec((u32)__shfl((int)evx, j0), d0, w0);
            uint4 z0 = dzq[(size_t)d0 * 16 + u];
            float w1 = 0.f; uint4 z1 = z0;
            if (iters > 1) {
                int dn;
                edec((u32)__shfl((int)evx, j0 + 4), dn, w1);
                z1 = dzq[(size_t)dn * 16 + u];
            }
            // prefetch NEXT node's first edge chunk now: its row ptrs were
            // issued at loop top; consumption is a whole node away.
            if (base == e0c) {
                ev = 0u;
                if (nn < NND) {
                    int cn = min(64, e1 - e0);
                    if (lane < cn) ev = esort[e0 + lane];
                }
            }
            int jj = j0;
            for (int k = 0; k < iters; ++k) {
                float w2 = 0.f; uint4 z2 = z0;
                if (k + 2 < iters) {                // wave-uniform
                    int dn;
                    edec((u32)__shfl((int)evx, jj + 8), dn, w2);
                    z2 = dzq[(size_t)dn * 16 + u];
                }
                a00 += silu_f(w0 * (s00 - blo(z0.x)));
                a01 += silu_f(w0 * (s01 - bhi(z0.x)));
                a02 += silu_f(w0 * (s02 - blo(z0.y)));
                a03 += silu_f(w0 * (s03 - bhi(z0.y)));
                a10 += silu_f(w0 * (s10 - blo(z0.z)));
                a11 += silu_f(w0 * (s11 - bhi(z0.z)));
                a12 += silu_f(w0 * (s12 - blo(z0.w)));
                a13 += silu_f(w0 * (s13 - bhi(z0.w)));
                jj += 4;
                w0 = w1; z0 = z1;
                w1 = w2; z1 = z2;
            }
        }

        a00 += __shfl_xor(a00, 16); a00 += __shfl_xor(a00, 32);
        a01 += __shfl_xor(a01, 16); a01 += __shfl_xor(a01, 32);
        a02 += __shfl_xor(a02, 16); a02 += __shfl_xor(a02, 32);
        a03 += __shfl_xor(a03, 16); a03 += __shfl_xor(a03, 32);
        a10 += __shfl_xor(a10, 16); a10 += __shfl_xor(a10, 32);
        a11 += __shfl_xor(a11, 16); a11 += __shfl_xor(a11, 32);
        a12 += __shfl_xor(a12, 16); a12 += __shfl_xor(a12, 32);
        a13 += __shfl_xor(a13, 16); a13 += __shfl_xor(a13, 32);
        if (g == 0) {
            sAg[wv][0][2 * u]     = a00; sAg[wv][1][2 * u]     = a01;
            sAg[wv][2][2 * u]     = a02; sAg[wv][3][2 * u]     = a03;
            sAg[wv][0][2 * u + 1] = a10; sAg[wv][1][2 * u + 1] = a11;
            sAg[wv][2][2 * u + 1] = a12; sAg[wv][3][2 * u + 1] = a13;
        }
        int lA = h, lB = h + 2;
        float yA = 0.f, yB = 0.f;
#pragma unroll
        for (int k = 0; k < CC; ++k) {
            yA += sAg[wv][lA][k] * sKt[lA][k][c];
            yB += sAg[wv][lB][k] * sKt[lB][k][c];
        }
        yA = -yA; yB = -yB;
        float yAo = __shfl_xor(yA, 32);
        float yBo = __shfl_xor(yB, 32);
        if (h == 0) {
            float y0 = yA, y1 = yAo, y2 = yB, y3 = yBo;
            y3 += X[n * CC + c];
            const float c0 = 0.70710678118654752f;  // sqrt(1/2)
            const float c1 = 0.81649658092772603f;  // sqrt(2/3)
            const float c2 = 0.86602540378443865f;  // sqrt(3/4)
            const float c3 = 0.89442719099991588f;  // sqrt(4/5)
            float t0 = c0 * y0;
            float t1 = c1 * (c0 * t0 + y1);
            float t2 = c2 * (c1 * t1 + y2);
            float t3 = c3 * (c2 * t2 + y3);
            float w3 = c3 * t3;
            float w2 = c2 * (c2 * w3 + t2);
            float w1 = c1 * (c1 * w2 + t1);
            float w0 = c0 * (c0 * w1 + t0);
            if (EPI == 0) {
                // pack bf16 row into LDS; stored as full lines below
                sZr[wv][0 * CC + c] = f2bfraw(w0);
                sZr[wv][1 * CC + c] = f2bfraw(w1);
                sZr[wv][2 * CC + c] = f2bfraw(w2);
                sZr[wv][3 * CC + c] = f2bfraw(w3);
            } else {
                int rem = n * CC + c;
                out[rem] = w3;                       // Z[3] block
                out[NC + 0 * NC + rem] = w0;         // Z flat (L,N,C)
                out[NC + 1 * NC + rem] = w1;
                out[NC + 2 * NC + rem] = w2;
                out[NC + 3 * NC + rem] = w3;
            }
        }
        if (EPI == 0) {
            asm volatile("s_waitcnt lgkmcnt(0)" ::: "memory");  // same-wave RAW
            if (lane < 16) {
                uint4 zv = *(const uint4*)(&sZr[wv][lane * 8]);
                ((uint4*)(Z + (size_t)n * 128))[lane] = zv;     // 2 full lines
            }
        }
    }
}

extern "C" void kernel_launch(void* const* d_in, const int* in_sizes, int n_in,
                              void* d_out, int out_size, void* d_ws, size_t ws_size,
                              hipStream_t stream)
{
    const float* X  = (const float*)d_in[0];
    const float* f  = (const float*)d_in[1];
    const int* ei   = (const int*)d_in[2];
    const float* ew = (const float*)d_in[3];
    const float* K  = (const float*)d_in[4];
    const float* Kf = (const float*)d_in[5];
    float* out = (float*)d_out;

    // ws layout (~46 MB of the >=51.2 MB workspace):
    //   dz 25.6 | fb 6.4 | frags 24K | ints ~0.8 | esort 6.4 | rank 6.4 MB
    char* ws = (char*)d_ws;
    uint2* dzv = (uint2*)ws;                                 // [N][C] ushort4
    const uint4* dzq = (const uint4*)ws;
    u16* fb        = (u16*)(ws + (size_t)NC * 8);            // NC bf16
    u16* KfFrag    = fb + NC;                                // 8192 u16
    u16* KFrag     = KfFrag + 16 * 64 * 8;                   // 4096 u16 (contiguous!)
    int* hist      = (int*)(KFrag + 8 * 64 * 8);             // NND
    int* row_start = hist + NND;                             // NND+1
    int* partial   = row_start + (NND + 1);                  // NBLK
    int* poffset   = partial + NBLK;                         // NBLK
    size_t eoff = ((size_t)((char*)(poffset + NBLK) - ws) + 15) & ~(size_t)15;
    u32* esort     = (u32*)(ws + eoff);                      // NE u32 = 6.4 MB
    int* rank      = (int*)(esort + NE);                     // NE int = 6.4 MB

    // Z bf16 [N][L][C] = 25.6 MB lives in d_out scratch; fully written by
    // edgetri<0>, fully read by node_mfma<false>, dead before edgetri<1>
    // overwrites d_out with the final fp32 output.
    u16* Z = (u16*)d_out;

    const int* ei0 = ei;
    const int* ei1 = ei + NE;

    hipMemsetAsync(hist, 0, (size_t)NND * sizeof(int), stream);

    // one-time prep: CSR sort (rank-based, atomic-free scatter) + bf16 conv
    histrank_kernel<<<NE / 256, 256, 0, stream>>>(ei0, hist, rank);
    reduce_kernel<<<NBLK, 256, 0, stream>>>(hist, partial);
    scanp_kernel<<<1, 512, 0, stream>>>(partial, poffset, row_start);
    scanb_kernel<<<NBLK, 256, 0, stream>>>(hist, poffset, row_start);
    scatter_kernel<<<NE / 256, 256, 0, stream>>>(ei0, ei1, ew, row_start, rank,
                                                 esort, f, (u32*)fb);
    prepw_kernel<<<1, 256, 0, stream>>>(K, Kf, KfFrag, KFrag);

    // fixpoint iteration 0: Z == 0 (no memset, no Z reads)
    node_mfma_kernel<true><<<1563, 256, 0, stream>>>((const u16*)Z, fb, KfFrag, dzv);
    edgetri_kernel<0><<<ETGRID, 256, 0, stream>>>(dzq, row_start, esort, K, X, Z, out);
    // fixpoint iteration 1: read Z, write final fp32 out directly
    node_mfma_kernel<false><<<1563, 256, 0, stream>>>((const u16*)Z, fb, KfFrag, dzv);
    edgetri_kernel<1><<<ETGRID, 256, 0, stream>>>(dzq, row_start, esort, K, X, Z, out);
}